// Round 5
// baseline (85.455 us; speedup 1.0000x reference)
//
#include <hip/hip_runtime.h>
#include <stdint.h>

// SampleChamfer: out = sum_i min_k ||pa_i - pb_k||^2
// pa_i = a[:, a_idx[i]], pb_k = b[:, b_idx[k]], fp32 scalar out.
//
// d = sq_a[i] + (sq_b[k] - 2*dot(pb_k, pa_i)); min over k; sum over i.
//
// 2 dispatches, no memsets:
//  P: gather ONCE -> pa4[i]=(ax,ay,az,||a||^2), pb4[i]=(-2bx,-2by,-2bz,||b||^2);
//     inits minarr[i]=0xFFFFFFFF (encoded +inf), counters[8]=0, d_out=0.
//  M: grid 8 a-chunks x 128 b-chunks = 1024 blocks (4/CU). 64 b-points in LDS,
//     4 a-points/thread in registers; cross-b-chunk combine via fire-and-forget
//     atomicMin on an order-preserving uint encoding (exact: int min is
//     associative). Last-finishing block per a-chunk (counter handshake,
//     release via __threadfence, reads via agent-scope atomic loads so no
//     stale XCD-L2 lines) reduces its chunk's 1024 mins + ||a||^2 and
//     atomicAdds into d_out.

#define BLOCK   256
#define NPTS_A  4     // a-points per thread -> 1024 a-points/block, 8 a-chunks
#define BPTS    64    // b-points per block  -> 128 b-chunks; grid = 1024

// Order-preserving float -> uint32 (monotone for all floats incl. negatives)
__device__ __forceinline__ unsigned enc_f32(float f) {
    unsigned u = __float_as_uint(f);
    return (u & 0x80000000u) ? ~u : (u | 0x80000000u);
}
__device__ __forceinline__ float dec_f32(unsigned u) {
    return (u & 0x80000000u) ? __uint_as_float(u & 0x7FFFFFFFu)
                             : __uint_as_float(~u);
}

__global__ __launch_bounds__(BLOCK)
void chamfer_pack_kernel(const float* __restrict__ a,
                         const float* __restrict__ b,
                         const int* __restrict__ a_idx,
                         const int* __restrict__ b_idx,
                         float4* __restrict__ pa4,
                         float4* __restrict__ pb4,
                         unsigned* __restrict__ minarr,
                         unsigned* __restrict__ counters,
                         float* __restrict__ out,
                         int N, int n, int a_chunks) {
    int i = blockIdx.x * BLOCK + threadIdx.x;
    if (i < n) {
        int ai = a_idx[i];
        float x = a[ai], y = a[N + ai], z = a[2 * N + ai];
        pa4[i] = make_float4(x, y, z, x * x + y * y + z * z);
        int bi = b_idx[i];
        float u = b[bi], v = b[N + bi], w = b[2 * N + bi];
        pb4[i] = make_float4(-2.f * u, -2.f * v, -2.f * w,
                             u * u + v * v + w * w);
        minarr[i] = 0xFFFFFFFFu;            // encoded +max
    }
    if (i < a_chunks) counters[i] = 0u;
    if (i == 0) out[0] = 0.f;               // d_out is poisoned each iter
}

__global__ __launch_bounds__(BLOCK)
void chamfer_min_kernel(const float4* __restrict__ pa4,
                        const float4* __restrict__ pb4,
                        unsigned* __restrict__ minarr,
                        unsigned* __restrict__ counters,
                        float* __restrict__ out,
                        int a_chunks, int b_chunks) {
    __shared__ float4 tile[BPTS];
    __shared__ int s_won;
    __shared__ float wsum[BLOCK / 64];
    const int bid = blockIdx.x;
    const int ac  = bid % a_chunks;
    const int bc  = bid / a_chunks;
    const int tid = threadIdx.x;
    const int APB = BLOCK * NPTS_A;          // a-points per block (1024)

    if (tid < BPTS)
        tile[tid] = pb4[bc * BPTS + tid];    // coalesced float4 copy
    __syncthreads();

    float ax[NPTS_A], ay[NPTS_A], az[NPTS_A], mn[NPTS_A];
#pragma unroll
    for (int m = 0; m < NPTS_A; ++m) {
        float4 p = pa4[ac * APB + m * BLOCK + tid];   // coalesced float4
        ax[m] = p.x; ay[m] = p.y; az[m] = p.z;
        mn[m] = 3.4e38f;
    }

    // 1 broadcast ds_read_b128 per k serves 4 a-points x 4 VALU ops.
#pragma unroll 8
    for (int k = 0; k < BPTS; ++k) {
        float4 t = tile[k];
#pragma unroll
        for (int m = 0; m < NPTS_A; ++m) {
            float c = fmaf(t.x, ax[m], fmaf(t.y, ay[m], fmaf(t.z, az[m], t.w)));
            mn[m] = fminf(mn[m], c);
        }
    }

    // Fire-and-forget, coalesced across lanes; device-scope by default.
#pragma unroll
    for (int m = 0; m < NPTS_A; ++m)
        atomicMin(&minarr[ac * APB + m * BLOCK + tid], enc_f32(mn[m]));

    // ---- last-block-per-chunk handshake ----
    __syncthreads();                 // all block's atomics issued & drained
    if (tid == 0) {
        __threadfence();             // release our mins to device scope
        unsigned old = atomicAdd(&counters[ac], 1u);
        s_won = (old == (unsigned)(b_chunks - 1));
    }
    __syncthreads();
    if (!s_won) return;

    // We are the last block for a-chunk ac: all 128 blocks' atomicMins are
    // visible (each incremented AFTER a release fence). Read minarr with
    // agent-scope atomic loads (bypasses potentially-stale non-coherent L2).
    __threadfence();                 // acquire
    float v = 0.f;
#pragma unroll
    for (int m = 0; m < NPTS_A; ++m) {
        int i = ac * APB + m * BLOCK + tid;
        unsigned u = __hip_atomic_load(&minarr[i], __ATOMIC_RELAXED,
                                       __HIP_MEMORY_SCOPE_AGENT);
        v += dec_f32(u) + pa4[i].w;
    }
#pragma unroll
    for (int off = 32; off > 0; off >>= 1)
        v += __shfl_down(v, off, 64);
    if ((tid & 63) == 0) wsum[tid >> 6] = v;
    __syncthreads();
    if (tid == 0) {
        float s = 0.f;
#pragma unroll
        for (int w = 0; w < BLOCK / 64; ++w) s += wsum[w];
        atomicAdd(out, s);           // out pre-zeroed by pack kernel
    }
}

extern "C" void kernel_launch(void* const* d_in, const int* in_sizes, int n_in,
                              void* d_out, int out_size, void* d_ws, size_t ws_size,
                              hipStream_t stream) {
    const float* a     = (const float*)d_in[0];
    const float* b     = (const float*)d_in[1];
    const int*   a_idx = (const int*)d_in[2];
    const int*   b_idx = (const int*)d_in[3];
    float*       out   = (float*)d_out;

    const int N = in_sizes[0] / 3;   // 16384
    const int n = in_sizes[2];       // 8192

    const int a_chunks = n / (BLOCK * NPTS_A);   // 8
    const int b_chunks = n / BPTS;               // 128

    // ws layout: pa4 [n], pb4 [n], minarr [n], counters [a_chunks]
    float4*   pa4      = (float4*)d_ws;
    float4*   pb4      = pa4 + n;
    unsigned* minarr   = (unsigned*)(pb4 + n);
    unsigned* counters = minarr + n;

    chamfer_pack_kernel<<<n / BLOCK, BLOCK, 0, stream>>>(
        a, b, a_idx, b_idx, pa4, pb4, minarr, counters, out, N, n, a_chunks);

    chamfer_min_kernel<<<a_chunks * b_chunks, BLOCK, 0, stream>>>(
        pa4, pb4, minarr, counters, out, a_chunks, b_chunks);
}

// Round 6
// 78.330 us; speedup vs baseline: 1.0910x; 1.0910x over previous
//
#include <hip/hip_runtime.h>
#include <stdint.h>

// SampleChamfer: out = sum_i min_k ||pa_i - pb_k||^2
// pa_i = a[:, a_idx[i]], pb_k = b[:, b_idx[k]], fp32 scalar out.
//
// d = sq_a[i] + (sq_b[k] - 2*dot(pb_k, pa_i)); min over k; sum over i.
//
// 2 dispatches, no memsets, NO device-scope fences (R5 post-mortem: per-block
// __threadfence = L2 wb/inv x1024 blocks = ~16us thrash):
//  P: 128x64 gather ONCE -> pa4[i]=(ax,ay,az,||a||^2),
//     pb4[i]=(-2bx,-2by,-2bz,||b||^2); init minarr=+inf(enc), counters=0, out=0.
//     Kernel boundary publishes everything (runtime release/acquire).
//  M: grid 8 a-chunks x 128 b-chunks = 1024 blocks (4/CU). 64 b-points in LDS,
//     4 a-points/thread in registers; cross-b-chunk combine via fire-and-forget
//     device-scope atomicMin on an order-preserving uint encoding (exact).
//     Coherence rides on the atomics: __syncthreads' implicit vmcnt(0) drain
//     completes this block's atomics at the coherent point BEFORE tid0's
//     relaxed counter bump. The 128th block per a-chunk reads minarr with
//     agent-scope relaxed atomic loads (bypasses stale L2 lines), adds
//     ||a||^2, block-sums, atomicAdds into pre-zeroed d_out.

#define BLOCK   256
#define NPTS_A  4     // a-points per thread -> 1024 a-points/block, 8 a-chunks
#define BPTS    64    // b-points per block  -> 128 b-chunks; grid = 1024

// Order-preserving float -> uint32 (monotone for all floats incl. negatives)
__device__ __forceinline__ unsigned enc_f32(float f) {
    unsigned u = __float_as_uint(f);
    return (u & 0x80000000u) ? ~u : (u | 0x80000000u);
}
__device__ __forceinline__ float dec_f32(unsigned u) {
    return (u & 0x80000000u) ? __uint_as_float(u & 0x7FFFFFFFu)
                             : __uint_as_float(~u);
}

__global__ __launch_bounds__(64)
void chamfer_pack_kernel(const float* __restrict__ a,
                         const float* __restrict__ b,
                         const int* __restrict__ a_idx,
                         const int* __restrict__ b_idx,
                         float4* __restrict__ pa4,
                         float4* __restrict__ pb4,
                         unsigned* __restrict__ minarr,
                         unsigned* __restrict__ counters,
                         float* __restrict__ out,
                         int N, int n, int a_chunks) {
    int i = blockIdx.x * 64 + threadIdx.x;   // 128 blocks x 64 thr: spread the
    if (i < n) {                             // latency-bound gathers over CUs
        int ai = a_idx[i];
        float x = a[ai], y = a[N + ai], z = a[2 * N + ai];
        pa4[i] = make_float4(x, y, z, x * x + y * y + z * z);
        int bi = b_idx[i];
        float u = b[bi], v = b[N + bi], w = b[2 * N + bi];
        pb4[i] = make_float4(-2.f * u, -2.f * v, -2.f * w,
                             u * u + v * v + w * w);
        minarr[i] = 0xFFFFFFFFu;            // encoded +max
    }
    if (i < a_chunks) counters[i] = 0u;
    if (i == 0) out[0] = 0.f;               // d_out is poisoned each iter
}

__global__ __launch_bounds__(BLOCK)
void chamfer_min_kernel(const float4* __restrict__ pa4,
                        const float4* __restrict__ pb4,
                        unsigned* __restrict__ minarr,
                        unsigned* __restrict__ counters,
                        float* __restrict__ out,
                        int a_chunks, int b_chunks) {
    __shared__ float4 tile[BPTS];
    __shared__ int s_won;
    __shared__ float wsum[BLOCK / 64];
    const int bid = blockIdx.x;
    const int ac  = bid % a_chunks;
    const int bc  = bid / a_chunks;
    const int tid = threadIdx.x;
    const int APB = BLOCK * NPTS_A;          // a-points per block (1024)

    if (tid < BPTS)
        tile[tid] = pb4[bc * BPTS + tid];    // coalesced float4 copy
    __syncthreads();

    float ax[NPTS_A], ay[NPTS_A], az[NPTS_A], mn[NPTS_A];
#pragma unroll
    for (int m = 0; m < NPTS_A; ++m) {
        float4 p = pa4[ac * APB + m * BLOCK + tid];   // coalesced float4
        ax[m] = p.x; ay[m] = p.y; az[m] = p.z;
        mn[m] = 3.4e38f;
    }

    // 1 broadcast ds_read_b128 per k serves 4 a-points x 4 VALU ops.
#pragma unroll 8
    for (int k = 0; k < BPTS; ++k) {
        float4 t = tile[k];
#pragma unroll
        for (int m = 0; m < NPTS_A; ++m) {
            float c = fmaf(t.x, ax[m], fmaf(t.y, ay[m], fmaf(t.z, az[m], t.w)));
            mn[m] = fminf(mn[m], c);
        }
    }

    // Fire-and-forget, device-scope (coherent point), coalesced across lanes.
#pragma unroll
    for (int m = 0; m < NPTS_A; ++m)
        atomicMin(&minarr[ac * APB + m * BLOCK + tid], enc_f32(mn[m]));

    // ---- last-block-per-chunk handshake, NO fences ----
    // __syncthreads() compiles to s_waitcnt vmcnt(0) + s_barrier: this block's
    // atomicMins are performed at the coherent point before the counter bump.
    __syncthreads();
    if (tid == 0) {
        unsigned old = __hip_atomic_fetch_add(&counters[ac], 1u,
                                              __ATOMIC_RELAXED,
                                              __HIP_MEMORY_SCOPE_AGENT);
        s_won = (old == (unsigned)(b_chunks - 1));
    }
    __syncthreads();
    if (!s_won) return;

    // Last block for a-chunk ac: all 128 blocks' atomicMins are at the
    // coherent point. Agent-scope atomic loads bypass stale L2 lines.
    float v = 0.f;
#pragma unroll
    for (int m = 0; m < NPTS_A; ++m) {
        int i = ac * APB + m * BLOCK + tid;
        unsigned u = __hip_atomic_load(&minarr[i], __ATOMIC_RELAXED,
                                       __HIP_MEMORY_SCOPE_AGENT);
        v += dec_f32(u) + pa4[i].w;          // pa4 read-only: clean L2 lines
    }
#pragma unroll
    for (int off = 32; off > 0; off >>= 1)
        v += __shfl_down(v, off, 64);
    if ((tid & 63) == 0) wsum[tid >> 6] = v;
    __syncthreads();
    if (tid == 0) {
        float s = 0.f;
#pragma unroll
        for (int w = 0; w < BLOCK / 64; ++w) s += wsum[w];
        atomicAdd(out, s);                   // out pre-zeroed by pack kernel
    }
}

extern "C" void kernel_launch(void* const* d_in, const int* in_sizes, int n_in,
                              void* d_out, int out_size, void* d_ws, size_t ws_size,
                              hipStream_t stream) {
    const float* a     = (const float*)d_in[0];
    const float* b     = (const float*)d_in[1];
    const int*   a_idx = (const int*)d_in[2];
    const int*   b_idx = (const int*)d_in[3];
    float*       out   = (float*)d_out;

    const int N = in_sizes[0] / 3;   // 16384
    const int n = in_sizes[2];       // 8192

    const int a_chunks = n / (BLOCK * NPTS_A);   // 8
    const int b_chunks = n / BPTS;               // 128

    // ws layout: pa4 [n], pb4 [n], minarr [n], counters [a_chunks]
    float4*   pa4      = (float4*)d_ws;
    float4*   pb4      = pa4 + n;
    unsigned* minarr   = (unsigned*)(pb4 + n);
    unsigned* counters = minarr + n;

    chamfer_pack_kernel<<<n / 64, 64, 0, stream>>>(
        a, b, a_idx, b_idx, pa4, pb4, minarr, counters, out, N, n, a_chunks);

    chamfer_min_kernel<<<a_chunks * b_chunks, BLOCK, 0, stream>>>(
        pa4, pb4, minarr, counters, out, a_chunks, b_chunks);
}

// Round 7
// 78.327 us; speedup vs baseline: 1.0910x; 1.0000x over previous
//
#include <hip/hip_runtime.h>
#include <stdint.h>

// SampleChamfer: out = sum_i min_k ||pa_i - pb_k||^2
// pa_i = a[:, a_idx[i]], pb_k = b[:, b_idx[k]], fp32 scalar out.
//
// d = sq_a[i] + (sq_b[k] - 2*dot(pb_k, pa_i)); min over k; sum over i.
//
// 2 dispatches, no memsets, no cross-block dependencies (R6 post-mortem:
// handshake fusion cost more than the dispatch it saved):
//  P: 32x256: gather b ONCE -> pb4[k]=(-2bx,-2by,-2bz,||b||^2); zero d_out.
//  M: 512 blocks x 256 thr; block owns 16 a-points (gathered in-block, no
//     redundancy), streams ALL pb4 coalesced (64 MB aggregate, L2-resident);
//     16 running mins in VGPRs -> 64 VALU ops per float4 load; butterfly
//     min across the wave, LDS combine across 4 waves, + ||a||^2, one
//     atomicAdd per block into pre-zeroed d_out. Min over b is block-local:
//     NO minarr, NO atomicMin, NO handshake.

#define BLOCK   256
#define APB     16            // a-points per block -> 512 blocks
#define BITERS  (8192 / BLOCK) // 32 b-iterations per thread

__global__ __launch_bounds__(BLOCK)
void chamfer_pack_kernel(const float* __restrict__ b,
                         const int* __restrict__ b_idx,
                         float4* __restrict__ pb4,
                         float* __restrict__ out,
                         int N, int n) {
    int i = blockIdx.x * BLOCK + threadIdx.x;
    if (i < n) {
        int bi = b_idx[i];
        float u = b[bi], v = b[N + bi], w = b[2 * N + bi];
        pb4[i] = make_float4(-2.f * u, -2.f * v, -2.f * w,
                             u * u + v * v + w * w);
    }
    if (i == 0) out[0] = 0.f;    // d_out is poisoned each iter
}

__global__ __launch_bounds__(BLOCK)
void chamfer_min_kernel(const float* __restrict__ a,
                        const int* __restrict__ a_idx,
                        const float4* __restrict__ pb4,
                        float* __restrict__ out,
                        int N, int n) {
    __shared__ float4 la[APB];            // (ax,ay,az,||a||^2) x 16
    __shared__ float  wmin[4][APB];       // per-wave mins
    const int tid  = threadIdx.x;
    const int lane = tid & 63;
    const int wv   = tid >> 6;

    // Block-local gather of its 16 a-points (once, zero redundancy).
    if (tid < APB) {
        int ai = a_idx[blockIdx.x * APB + tid];
        float x = a[ai], y = a[N + ai], z = a[2 * N + ai];
        la[tid] = make_float4(x, y, z, x * x + y * y + z * z);
    }
    __syncthreads();

    // Hoist the 16 a-points into registers (broadcast ds_read_b128).
    float4 ap[APB];
#pragma unroll
    for (int j = 0; j < APB; ++j) ap[j] = la[j];

    float mn[APB];
#pragma unroll
    for (int j = 0; j < APB; ++j) mn[j] = 3.4e38f;

    // Stream all 8192 b-points, coalesced float4; 64 VALU ops per load.
    const float4* pb = pb4 + tid;
#pragma unroll 2
    for (int it = 0; it < BITERS; ++it) {
        float4 t = pb[it * BLOCK];
#pragma unroll
        for (int j = 0; j < APB; ++j) {
            float c = fmaf(t.x, ap[j].x,
                      fmaf(t.y, ap[j].y,
                      fmaf(t.z, ap[j].z, t.w)));
            mn[j] = fminf(mn[j], c);
        }
    }

    // 64-lane butterfly min for each of the 16 a-points.
#pragma unroll
    for (int j = 0; j < APB; ++j) {
#pragma unroll
        for (int off = 1; off < 64; off <<= 1)
            mn[j] = fminf(mn[j], __shfl_xor(mn[j], off, 64));
    }
    // After butterfly every lane has the wave-min; lane j stores slot j.
    if (lane < APB) wmin[wv][lane] = mn[lane];
    __syncthreads();

    // Wave 0: combine 4 waves, add ||a||^2, sum 16, one atomicAdd.
    if (tid < APB) {
        float m = fminf(fminf(wmin[0][tid], wmin[1][tid]),
                        fminf(wmin[2][tid], wmin[3][tid]));
        float v = m + la[tid].w;
#pragma unroll
        for (int off = 1; off < APB; off <<= 1)
            v += __shfl_xor(v, off, 64);
        if (tid == 0) atomicAdd(out, v);   // out pre-zeroed by pack kernel
    }
}

extern "C" void kernel_launch(void* const* d_in, const int* in_sizes, int n_in,
                              void* d_out, int out_size, void* d_ws, size_t ws_size,
                              hipStream_t stream) {
    const float* a     = (const float*)d_in[0];
    const float* b     = (const float*)d_in[1];
    const int*   a_idx = (const int*)d_in[2];
    const int*   b_idx = (const int*)d_in[3];
    float*       out   = (float*)d_out;

    const int N = in_sizes[0] / 3;   // 16384
    const int n = in_sizes[2];       // 8192

    float4* pb4 = (float4*)d_ws;     // [n] = 128 KB

    chamfer_pack_kernel<<<n / BLOCK, BLOCK, 0, stream>>>(
        b, b_idx, pb4, out, N, n);

    chamfer_min_kernel<<<n / APB, BLOCK, 0, stream>>>(
        a, a_idx, pb4, out, N, n);
}

// Round 8
// 69.481 us; speedup vs baseline: 1.2299x; 1.1273x over previous
//
#include <hip/hip_runtime.h>
#include <stdint.h>

// SampleChamfer: out = sum_i min_k ||pa_i - pb_k||^2
// pa_i = a[:, a_idx[i]], pb_k = b[:, b_idx[k]], fp32 scalar out.
//
// d = sq_a[i] + (sq_b[k] - 2*dot(pb_k, pa_i)); min over k; sum over i.
//
// R4 composition (best measured: 69.7 us) restored verbatim, except the pack
// kernel grid is 64x128 instead of 32x256 (spread latency-bound gathers over
// 2x CUs; same work). 3 dispatches, no memsets, no fences, no handshake:
//  P: gather ONCE -> pa4[i]=(ax,ay,az,||a||^2), pb4[i]=(-2bx,-2by,-2bz,||b||^2);
//     inits minarr[i]=0xFFFFFFFF (encoded +inf), zeroes d_out.
//  M: grid 8 a-chunks x 128 b-chunks = 1024 blocks (4/CU). 64 b-points in LDS,
//     4 a-points/thread in registers; cross-b-chunk combine via fire-and-forget
//     device-scope atomicMin on an order-preserving uint encoding (exact:
//     integer min is associative; deterministic).
//  R: 32 blocks decode minarr (plain loads — kernel boundary publishes),
//     add ||a||^2, block-sum, atomicAdd -> pre-zeroed d_out.

#define BLOCK   256
#define NPTS_A  4     // a-points per thread -> 1024 a-points/block, 8 a-chunks
#define BPTS    64    // b-points per block  -> 128 b-chunks; grid = 1024

// Order-preserving float -> uint32 (monotone for all floats incl. negatives)
__device__ __forceinline__ unsigned enc_f32(float f) {
    unsigned u = __float_as_uint(f);
    return (u & 0x80000000u) ? ~u : (u | 0x80000000u);
}
__device__ __forceinline__ float dec_f32(unsigned u) {
    return (u & 0x80000000u) ? __uint_as_float(u & 0x7FFFFFFFu)
                             : __uint_as_float(~u);
}

__global__ __launch_bounds__(128)
void chamfer_pack_kernel(const float* __restrict__ a,
                         const float* __restrict__ b,
                         const int* __restrict__ a_idx,
                         const int* __restrict__ b_idx,
                         float4* __restrict__ pa4,
                         float4* __restrict__ pb4,
                         unsigned* __restrict__ minarr,
                         float* __restrict__ out,
                         int N, int n) {
    int i = blockIdx.x * 128 + threadIdx.x;   // 64 blocks x 128 threads
    if (i < n) {
        int ai = a_idx[i];
        float x = a[ai], y = a[N + ai], z = a[2 * N + ai];
        pa4[i] = make_float4(x, y, z, x * x + y * y + z * z);
        int bi = b_idx[i];
        float u = b[bi], v = b[N + bi], w = b[2 * N + bi];
        pb4[i] = make_float4(-2.f * u, -2.f * v, -2.f * w,
                             u * u + v * v + w * w);
        minarr[i] = 0xFFFFFFFFu;            // encoded +max
    }
    if (i == 0) out[0] = 0.f;               // d_out is poisoned each iter
}

__global__ __launch_bounds__(BLOCK)
void chamfer_min_kernel(const float4* __restrict__ pa4,
                        const float4* __restrict__ pb4,
                        unsigned* __restrict__ minarr,
                        int a_chunks) {
    __shared__ float4 tile[BPTS];
    const int bid = blockIdx.x;
    const int ac  = bid % a_chunks;
    const int bc  = bid / a_chunks;
    const int tid = threadIdx.x;
    const int APB = BLOCK * NPTS_A;          // a-points per block (1024)

    if (tid < BPTS)
        tile[tid] = pb4[bc * BPTS + tid];    // coalesced float4 copy
    __syncthreads();

    float ax[NPTS_A], ay[NPTS_A], az[NPTS_A], mn[NPTS_A];
#pragma unroll
    for (int m = 0; m < NPTS_A; ++m) {
        float4 p = pa4[ac * APB + m * BLOCK + tid];   // coalesced float4
        ax[m] = p.x; ay[m] = p.y; az[m] = p.z;
        mn[m] = 3.4e38f;
    }

    // 1 broadcast ds_read_b128 per k serves 4 a-points x 4 VALU ops.
#pragma unroll 8
    for (int k = 0; k < BPTS; ++k) {
        float4 t = tile[k];
#pragma unroll
        for (int m = 0; m < NPTS_A; ++m) {
            float c = fmaf(t.x, ax[m], fmaf(t.y, ay[m], fmaf(t.z, az[m], t.w)));
            mn[m] = fminf(mn[m], c);
        }
    }

    // Fire-and-forget (no return value -> no wait), coalesced across lanes.
#pragma unroll
    for (int m = 0; m < NPTS_A; ++m)
        atomicMin(&minarr[ac * APB + m * BLOCK + tid], enc_f32(mn[m]));
}

__global__ __launch_bounds__(BLOCK)
void chamfer_reduce_kernel(const float4* __restrict__ pa4,
                           const unsigned* __restrict__ minarr,
                           float* __restrict__ out) {
    __shared__ float wsum[BLOCK / 64];
    const int tid = threadIdx.x;
    const int i = blockIdx.x * BLOCK + tid;

    float v = dec_f32(minarr[i]) + pa4[i].w;

#pragma unroll
    for (int off = 32; off > 0; off >>= 1)
        v += __shfl_down(v, off, 64);
    if ((tid & 63) == 0) wsum[tid >> 6] = v;
    __syncthreads();
    if (tid == 0) {
        float s = 0.f;
#pragma unroll
        for (int w = 0; w < BLOCK / 64; ++w) s += wsum[w];
        atomicAdd(out, s);                   // out pre-zeroed by pack kernel
    }
}

extern "C" void kernel_launch(void* const* d_in, const int* in_sizes, int n_in,
                              void* d_out, int out_size, void* d_ws, size_t ws_size,
                              hipStream_t stream) {
    const float* a     = (const float*)d_in[0];
    const float* b     = (const float*)d_in[1];
    const int*   a_idx = (const int*)d_in[2];
    const int*   b_idx = (const int*)d_in[3];
    float*       out   = (float*)d_out;

    const int N = in_sizes[0] / 3;   // 16384
    const int n = in_sizes[2];       // 8192

    const int a_chunks = n / (BLOCK * NPTS_A);   // 8

    // ws layout: pa4 [n], pb4 [n], minarr [n]
    float4*   pa4    = (float4*)d_ws;
    float4*   pb4    = pa4 + n;
    unsigned* minarr = (unsigned*)(pb4 + n);

    chamfer_pack_kernel<<<n / 128, 128, 0, stream>>>(
        a, b, a_idx, b_idx, pa4, pb4, minarr, out, N, n);

    chamfer_min_kernel<<<a_chunks * (n / BPTS), BLOCK, 0, stream>>>(
        pa4, pb4, minarr, a_chunks);

    chamfer_reduce_kernel<<<n / BLOCK, BLOCK, 0, stream>>>(
        pa4, minarr, out);
}